// Round 1
// baseline (568.450 us; speedup 1.0000x reference)
//
#include <hip/hip_runtime.h>
#include <stdint.h>

typedef __attribute__((ext_vector_type(8))) short short8;
typedef __attribute__((ext_vector_type(4))) short short4v;
typedef __attribute__((ext_vector_type(4))) float floatx4;

#define LOG2E 1.44269504088896f

__device__ __forceinline__ unsigned short f2bf(float f) {
  unsigned int u = __float_as_uint(f);
  unsigned int r = (u + 0x7FFFu + ((u >> 16) & 1u)) >> 16;  // RNE
  return (unsigned short)r;
}

__device__ __forceinline__ void async_copy16(void* lds, const void* g) {
  __builtin_amdgcn_global_load_lds(
      (const __attribute__((address_space(1))) unsigned int*)g,
      (__attribute__((address_space(3))) unsigned int*)lds, 16, 0, 0);
}

// ---------------------------------------------------------------------------
// fp32 -> bf16 conversion (vectorized, grid-exact)
// ---------------------------------------------------------------------------
__global__ __launch_bounds__(256) void f2b_kernel(const float* __restrict__ in,
                                                  unsigned short* __restrict__ out,
                                                  int n4) {
  int i = blockIdx.x * 256 + threadIdx.x;
  if (i >= n4) return;
  float4 v = ((const float4*)in)[i];
  short4v o;
  o[0] = (short)f2bf(v.x);
  o[1] = (short)f2bf(v.y);
  o[2] = (short)f2bf(v.z);
  o[3] = (short)f2bf(v.w);
  *(short4v*)(out + (long)i * 4) = o;
}

// ---------------------------------------------------------------------------
// m97-structure GEMM mainloop: C[128x128] = A[128xK] * Bt[128xK]^T
// A row-major [M][K], Bt row-major [N][K] (i.e. B^T input). bf16 bits.
// 256 threads = 4 waves in 2x2; each wave computes 64x64 via 4x4 MFMA frags.
// ---------------------------------------------------------------------------
__device__ __forceinline__ void gemm128_mainloop(
    const unsigned short* __restrict__ A, const unsigned short* __restrict__ Bt,
    int K, long brow, long bcol, unsigned short* As, unsigned short* Bs,
    floatx4 acc[4][4]) {
  const int tid = threadIdx.x;
  const int wave = tid >> 6;
  const int lane = tid & 63;
  const int wr = wave >> 1, wc = wave & 1;
  const int lr = lane & 15, lg = lane >> 4;

  const unsigned short* ga = A + (brow + (tid >> 2)) * (long)K + (tid & 3) * 8;
  const unsigned short* gb = Bt + (bcol + (tid >> 2)) * (long)K + (tid & 3) * 8;
  unsigned short* lA = As + wave * 512;  // wave-uniform LDS dest (lane*16B appended by HW)
  unsigned short* lB = Bs + wave * 512;
  const int a_off = (wr * 64 + lr) * 32 + lg * 8;
  const int b_off = (wc * 64 + lr) * 32 + lg * 8;

  for (int kt = 0; kt < K; kt += 32) {
    __syncthreads();
    async_copy16(lA, ga);
    async_copy16(lA + 2048, ga + (long)64 * K);
    async_copy16(lB, gb);
    async_copy16(lB + 2048, gb + (long)64 * K);
    ga += 32;
    gb += 32;
    __syncthreads();
    short8 af[4], bf[4];
#pragma unroll
    for (int i = 0; i < 4; ++i) {
      af[i] = *(const short8*)(As + a_off + i * 512);
      bf[i] = *(const short8*)(Bs + b_off + i * 512);
    }
#pragma unroll
    for (int i = 0; i < 4; ++i)
#pragma unroll
      for (int j = 0; j < 4; ++j)
        acc[i][j] = __builtin_amdgcn_mfma_f32_16x16x32_bf16(af[i], bf[j], acc[i][j], 0, 0, 0);
  }
}

// ---------------------------------------------------------------------------
// QKV projection: out col n in [0,3072): kind = n>>10 (Q/K/V), f = n&1023.
// Q,K stored [BH][T][64] bf16; V stored transposed [BH][64][T] bf16.
// ---------------------------------------------------------------------------
__global__ __launch_bounds__(256) void qkv_gemm(
    const unsigned short* __restrict__ xb, const unsigned short* __restrict__ wqkv,
    const float* __restrict__ bq, const float* __restrict__ bk,
    const float* __restrict__ bv, unsigned short* __restrict__ q_out,
    unsigned short* __restrict__ k_out, unsigned short* __restrict__ vt_out) {
  __shared__ unsigned short As[128 * 32];
  __shared__ unsigned short Bs[128 * 32];
  floatx4 zero = {0.f, 0.f, 0.f, 0.f};
  floatx4 acc[4][4];
#pragma unroll
  for (int i = 0; i < 4; ++i)
#pragma unroll
    for (int j = 0; j < 4; ++j) acc[i][j] = zero;

  long brow = (long)blockIdx.x * 128;
  long bcol = (long)blockIdx.y * 128;
  gemm128_mainloop(xb, wqkv, 1024, brow, bcol, As, Bs, acc);

  const int wave = threadIdx.x >> 6, lane = threadIdx.x & 63;
  const int wr = wave >> 1, wc = wave & 1, lr = lane & 15, lg = lane >> 4;
  const int kind = (int)(bcol >> 10);
  const float* bias = (kind == 0) ? bq : (kind == 1 ? bk : bv);
#pragma unroll
  for (int i = 0; i < 4; ++i)
#pragma unroll
    for (int j = 0; j < 4; ++j)
#pragma unroll
      for (int r = 0; r < 4; ++r) {
        int m = (int)brow + wr * 64 + i * 16 + lg * 4 + r;
        int n = (int)bcol + wc * 64 + j * 16 + lr;
        int f = n & 1023;
        float v = acc[i][j][r] + bias[f];
        unsigned short o = f2bf(v);
        int h = f >> 6, d = f & 63;
        int b = m >> 11, t = m & 2047;
        long bh = (long)(b * 16 + h);
        if (kind == 0)
          q_out[(bh * 2048 + t) * 64 + d] = o;
        else if (kind == 1)
          k_out[(bh * 2048 + t) * 64 + d] = o;
        else
          vt_out[(bh * 64 + d) * 2048 + t] = o;
      }
}

// ---------------------------------------------------------------------------
// Output projection: out = O @ Wo^T + bo, fp32 result.
// ---------------------------------------------------------------------------
__global__ __launch_bounds__(256) void out_gemm(
    const unsigned short* __restrict__ ob, const unsigned short* __restrict__ wo,
    const float* __restrict__ bo, float* __restrict__ out) {
  __shared__ unsigned short As[128 * 32];
  __shared__ unsigned short Bs[128 * 32];
  floatx4 zero = {0.f, 0.f, 0.f, 0.f};
  floatx4 acc[4][4];
#pragma unroll
  for (int i = 0; i < 4; ++i)
#pragma unroll
    for (int j = 0; j < 4; ++j) acc[i][j] = zero;

  long brow = (long)blockIdx.x * 128;
  long bcol = (long)blockIdx.y * 128;
  gemm128_mainloop(ob, wo, 1024, brow, bcol, As, Bs, acc);

  const int wave = threadIdx.x >> 6, lane = threadIdx.x & 63;
  const int wr = wave >> 1, wc = wave & 1, lr = lane & 15, lg = lane >> 4;
#pragma unroll
  for (int i = 0; i < 4; ++i)
#pragma unroll
    for (int j = 0; j < 4; ++j)
#pragma unroll
      for (int r = 0; r < 4; ++r) {
        int m = (int)brow + wr * 64 + i * 16 + lg * 4 + r;
        int n = (int)bcol + wc * 64 + j * 16 + lr;
        out[(long)m * 1024 + n] = acc[i][j][r] + bo[n];
      }
}

// ---------------------------------------------------------------------------
// Flash attention (causal). Grid: (T/64, B*H). 4 waves, wave w owns 16 q-rows.
// Q [BH][T][64], K [BH][T][64], Vt [BH][64][T] (all bf16 bits).
// Output O written as [B][T][H*64] bf16 (row-major for final GEMM).
// ---------------------------------------------------------------------------
__global__ __launch_bounds__(256) void attn_fwd(
    const unsigned short* __restrict__ qb, const unsigned short* __restrict__ kb,
    const unsigned short* __restrict__ vtb, unsigned short* __restrict__ ob) {
  const int qt = blockIdx.x;
  const int bh = blockIdx.y;
  const int wave = threadIdx.x >> 6, lane = threadIdx.x & 63;
  const int lr = lane & 15, lg = lane >> 4;
  const unsigned short* Q = qb + (long)bh * 2048 * 64;
  const unsigned short* Kp = kb + (long)bh * 2048 * 64;
  const unsigned short* Vt = vtb + (long)bh * 64 * 2048;
  const int q0 = qt * 64 + wave * 16;
  const int row_base = q0 + lg * 4;  // C-layout row for reg r: row_base + r

  // Q fragments (A-operand): rows q0+lr, k = kk*32 + lg*8 + j
  short8 qf0 = *(const short8*)(Q + (q0 + lr) * 64 + lg * 8);
  short8 qf1 = *(const short8*)(Q + (q0 + lr) * 64 + 32 + lg * 8);

  floatx4 zero = {0.f, 0.f, 0.f, 0.f};
  floatx4 accO[4];
#pragma unroll
  for (int dt = 0; dt < 4; ++dt) accO[dt] = zero;
  float m_i[4], l_i[4];
#pragma unroll
  for (int r = 0; r < 4; ++r) {
    m_i[r] = -1e30f;
    l_i[r] = 0.f;
  }

  // per-wave P^T buffer: PT[kv][q], q-stride padded 16->20 elems (bank spread)
  __shared__ unsigned short PT[4][64 * 20];
  unsigned short* PTw = PT[wave];

  for (int kv = 0; kv <= qt; ++kv) {
    const int kv0 = kv * 64;
    floatx4 s[4];
#pragma unroll
    for (int nt = 0; nt < 4; ++nt) {
      const unsigned short* kp = Kp + (kv0 + nt * 16 + lr) * 64 + lg * 8;
      short8 kf0 = *(const short8*)kp;
      short8 kf1 = *(const short8*)(kp + 32);
      floatx4 a = zero;
      a = __builtin_amdgcn_mfma_f32_16x16x32_bf16(qf0, kf0, a, 0, 0, 0);
      a = __builtin_amdgcn_mfma_f32_16x16x32_bf16(qf1, kf1, a, 0, 0, 0);
      s[nt] = a;
    }
    // scale + causal mask (only diagonal tile needs the compare)
    if (kv == qt) {
#pragma unroll
      for (int nt = 0; nt < 4; ++nt)
#pragma unroll
        for (int r = 0; r < 4; ++r) {
          int col = kv0 + nt * 16 + lr;
          s[nt][r] = (col <= row_base + r) ? s[nt][r] * 0.125f : -1e30f;
        }
    } else {
#pragma unroll
      for (int nt = 0; nt < 4; ++nt)
#pragma unroll
        for (int r = 0; r < 4; ++r) s[nt][r] *= 0.125f;
    }
    // online softmax: row stats across 16-lane groups
    float mnew[4], scl[4], rs[4];
#pragma unroll
    for (int r = 0; r < 4; ++r) {
      float mt = fmaxf(fmaxf(s[0][r], s[1][r]), fmaxf(s[2][r], s[3][r]));
      mt = fmaxf(mt, __shfl_xor(mt, 1));
      mt = fmaxf(mt, __shfl_xor(mt, 2));
      mt = fmaxf(mt, __shfl_xor(mt, 4));
      mt = fmaxf(mt, __shfl_xor(mt, 8));
      mnew[r] = fmaxf(m_i[r], mt);
      scl[r] = exp2f((m_i[r] - mnew[r]) * LOG2E);
      m_i[r] = mnew[r];
      rs[r] = 0.f;
    }
    // P = exp(s - m), write P^T to LDS (packed 4 rows -> one b64 per nt)
#pragma unroll
    for (int nt = 0; nt < 4; ++nt) {
      short4v pk;
#pragma unroll
      for (int r = 0; r < 4; ++r) {
        float p = exp2f((s[nt][r] - mnew[r]) * LOG2E);
        rs[r] += p;
        pk[r] = (short)f2bf(p);
      }
      *(short4v*)(PTw + (nt * 16 + lr) * 20 + lg * 4) = pk;
    }
#pragma unroll
    for (int r = 0; r < 4; ++r) {
      float t = rs[r];
      t += __shfl_xor(t, 1);
      t += __shfl_xor(t, 2);
      t += __shfl_xor(t, 4);
      t += __shfl_xor(t, 8);
      l_i[r] = l_i[r] * scl[r] + t;
#pragma unroll
      for (int dt = 0; dt < 4; ++dt) accO[dt][r] *= scl[r];
    }
    // PV: A = P (frag from LDS transpose), B = V (contiguous from Vt)
#pragma unroll
    for (int kk = 0; kk < 2; ++kk) {
      short8 pf;
#pragma unroll
      for (int jj = 0; jj < 8; ++jj)
        pf[jj] = (short)PTw[(kk * 32 + lg * 8 + jj) * 20 + lr];
      const unsigned short* vp = Vt + lr * 2048 + kv0 + kk * 32 + lg * 8;
#pragma unroll
      for (int dt = 0; dt < 4; ++dt) {
        short8 vf = *(const short8*)(vp + (long)dt * 16 * 2048);
        accO[dt] = __builtin_amdgcn_mfma_f32_16x16x32_bf16(pf, vf, accO[dt], 0, 0, 0);
      }
    }
  }
  // epilogue: O /= l, store [B][T][H*64]
  const int b = bh >> 4, h = bh & 15;
  float inv[4];
#pragma unroll
  for (int r = 0; r < 4; ++r) inv[r] = 1.f / l_i[r];
#pragma unroll
  for (int dt = 0; dt < 4; ++dt)
#pragma unroll
    for (int r = 0; r < 4; ++r) {
      int t = row_base + r;
      ob[((long)b * 2048 + t) * 1024 + h * 64 + dt * 16 + lr] =
          f2bf(accO[dt][r] * inv[r]);
    }
}

// ---------------------------------------------------------------------------
extern "C" void kernel_launch(void* const* d_in, const int* in_sizes, int n_in,
                              void* d_out, int out_size, void* d_ws, size_t ws_size,
                              hipStream_t stream) {
  const float* x = (const float*)d_in[0];
  const float* Wq = (const float*)d_in[1];
  const float* bq = (const float*)d_in[2];
  const float* Wk = (const float*)d_in[3];
  const float* bk = (const float*)d_in[4];
  const float* Wv = (const float*)d_in[5];
  const float* bv = (const float*)d_in[6];
  const float* Wo = (const float*)d_in[7];
  const float* bo = (const float*)d_in[8];
  float* out = (float*)d_out;

  char* ws = (char*)d_ws;
  unsigned short* xb = (unsigned short*)(ws);                  // 16 MB  [8192][1024]
  unsigned short* wqkv = (unsigned short*)(ws + (16l << 20));  // 6 MB   [3072][1024]
  unsigned short* wob = (unsigned short*)(ws + (22l << 20));   // 2 MB   [1024][1024]
  unsigned short* qb = (unsigned short*)(ws + (24l << 20));    // 16 MB  [64][2048][64]
  unsigned short* kb = (unsigned short*)(ws + (40l << 20));    // 16 MB  [64][2048][64]
  unsigned short* vtb = (unsigned short*)(ws + (56l << 20));   // 16 MB  [64][64][2048]
  unsigned short* ob = (unsigned short*)(ws + (72l << 20));    // 16 MB  [8192][1024]

  f2b_kernel<<<2097152 / 256, 256, 0, stream>>>(x, xb, 2097152);
  f2b_kernel<<<262144 / 256, 256, 0, stream>>>(Wq, wqkv, 262144);
  f2b_kernel<<<262144 / 256, 256, 0, stream>>>(Wk, wqkv + (1l << 20), 262144);
  f2b_kernel<<<262144 / 256, 256, 0, stream>>>(Wv, wqkv + (2l << 20), 262144);
  f2b_kernel<<<262144 / 256, 256, 0, stream>>>(Wo, wob, 262144);

  qkv_gemm<<<dim3(64, 24), 256, 0, stream>>>(xb, wqkv, bq, bk, bv, qb, kb, vtb);
  attn_fwd<<<dim3(32, 64), 256, 0, stream>>>(qb, kb, vtb, ob);
  out_gemm<<<dim3(64, 8), 256, 0, stream>>>(ob, wob, bo, out);
}

// Round 2
// 366.681 us; speedup vs baseline: 1.5503x; 1.5503x over previous
//
#include <hip/hip_runtime.h>
#include <stdint.h>

typedef __attribute__((ext_vector_type(8))) short short8;
typedef __attribute__((ext_vector_type(4))) short short4v;
typedef __attribute__((ext_vector_type(4))) float floatx4;

#define LOG2E 1.44269504088896f

__device__ __forceinline__ unsigned short f2bf(float f) {
  unsigned int u = __float_as_uint(f);
  unsigned int r = (u + 0x7FFFu + ((u >> 16) & 1u)) >> 16;  // RNE
  return (unsigned short)r;
}

__device__ __forceinline__ void async_copy16(void* lds, const void* g) {
  __builtin_amdgcn_global_load_lds(
      (const __attribute__((address_space(1))) unsigned int*)g,
      (__attribute__((address_space(3))) unsigned int*)lds, 16, 0, 0);
}

// ---------------------------------------------------------------------------
// fp32 -> bf16 conversion (vectorized, grid-exact)
// ---------------------------------------------------------------------------
__global__ __launch_bounds__(256) void f2b_kernel(const float* __restrict__ in,
                                                  unsigned short* __restrict__ out,
                                                  int n4) {
  int i = blockIdx.x * 256 + threadIdx.x;
  if (i >= n4) return;
  float4 v = ((const float4*)in)[i];
  short4v o;
  o[0] = (short)f2bf(v.x);
  o[1] = (short)f2bf(v.y);
  o[2] = (short)f2bf(v.z);
  o[3] = (short)f2bf(v.w);
  *(short4v*)(out + (long)i * 4) = o;
}

// ---------------------------------------------------------------------------
// m97-structure GEMM mainloop: C[128x128] = A[128xK] * Bt[128xK]^T
// ---------------------------------------------------------------------------
__device__ __forceinline__ void gemm128_mainloop(
    const unsigned short* __restrict__ A, const unsigned short* __restrict__ Bt,
    int K, long brow, long bcol, unsigned short* As, unsigned short* Bs,
    floatx4 acc[4][4]) {
  const int tid = threadIdx.x;
  const int wave = tid >> 6;
  const int lane = tid & 63;
  const int wr = wave >> 1, wc = wave & 1;
  const int lr = lane & 15, lg = lane >> 4;

  const unsigned short* ga = A + (brow + (tid >> 2)) * (long)K + (tid & 3) * 8;
  const unsigned short* gb = Bt + (bcol + (tid >> 2)) * (long)K + (tid & 3) * 8;
  unsigned short* lA = As + wave * 512;
  unsigned short* lB = Bs + wave * 512;
  const int a_off = (wr * 64 + lr) * 32 + lg * 8;
  const int b_off = (wc * 64 + lr) * 32 + lg * 8;

  for (int kt = 0; kt < K; kt += 32) {
    __syncthreads();
    async_copy16(lA, ga);
    async_copy16(lA + 2048, ga + (long)64 * K);
    async_copy16(lB, gb);
    async_copy16(lB + 2048, gb + (long)64 * K);
    ga += 32;
    gb += 32;
    __syncthreads();
    short8 af[4], bf[4];
#pragma unroll
    for (int i = 0; i < 4; ++i) {
      af[i] = *(const short8*)(As + a_off + i * 512);
      bf[i] = *(const short8*)(Bs + b_off + i * 512);
    }
#pragma unroll
    for (int i = 0; i < 4; ++i)
#pragma unroll
      for (int j = 0; j < 4; ++j)
        acc[i][j] = __builtin_amdgcn_mfma_f32_16x16x32_bf16(af[i], bf[j], acc[i][j], 0, 0, 0);
  }
}

// ---------------------------------------------------------------------------
// QKV projection
// ---------------------------------------------------------------------------
__global__ __launch_bounds__(256) void qkv_gemm(
    const unsigned short* __restrict__ xb, const unsigned short* __restrict__ wqkv,
    const float* __restrict__ bq, const float* __restrict__ bk,
    const float* __restrict__ bv, unsigned short* __restrict__ q_out,
    unsigned short* __restrict__ k_out, unsigned short* __restrict__ vt_out) {
  __shared__ unsigned short As[128 * 32];
  __shared__ unsigned short Bs[128 * 32];
  floatx4 zero = {0.f, 0.f, 0.f, 0.f};
  floatx4 acc[4][4];
#pragma unroll
  for (int i = 0; i < 4; ++i)
#pragma unroll
    for (int j = 0; j < 4; ++j) acc[i][j] = zero;

  long brow = (long)blockIdx.x * 128;
  long bcol = (long)blockIdx.y * 128;
  gemm128_mainloop(xb, wqkv, 1024, brow, bcol, As, Bs, acc);

  const int wave = threadIdx.x >> 6, lane = threadIdx.x & 63;
  const int wr = wave >> 1, wc = wave & 1, lr = lane & 15, lg = lane >> 4;
  const int kind = (int)(bcol >> 10);
  const float* bias = (kind == 0) ? bq : (kind == 1 ? bk : bv);
#pragma unroll
  for (int i = 0; i < 4; ++i)
#pragma unroll
    for (int j = 0; j < 4; ++j)
#pragma unroll
      for (int r = 0; r < 4; ++r) {
        int m = (int)brow + wr * 64 + i * 16 + lg * 4 + r;
        int n = (int)bcol + wc * 64 + j * 16 + lr;
        int f = n & 1023;
        float v = acc[i][j][r] + bias[f];
        unsigned short o = f2bf(v);
        int h = f >> 6, d = f & 63;
        int b = m >> 11, t = m & 2047;
        long bh = (long)(b * 16 + h);
        if (kind == 0)
          q_out[(bh * 2048 + t) * 64 + d] = o;
        else if (kind == 1)
          k_out[(bh * 2048 + t) * 64 + d] = o;
        else
          vt_out[(bh * 64 + d) * 2048 + t] = o;
      }
}

// ---------------------------------------------------------------------------
// Output projection
// ---------------------------------------------------------------------------
__global__ __launch_bounds__(256) void out_gemm(
    const unsigned short* __restrict__ ob, const unsigned short* __restrict__ wo,
    const float* __restrict__ bo, float* __restrict__ out) {
  __shared__ unsigned short As[128 * 32];
  __shared__ unsigned short Bs[128 * 32];
  floatx4 zero = {0.f, 0.f, 0.f, 0.f};
  floatx4 acc[4][4];
#pragma unroll
  for (int i = 0; i < 4; ++i)
#pragma unroll
    for (int j = 0; j < 4; ++j) acc[i][j] = zero;

  long brow = (long)blockIdx.x * 128;
  long bcol = (long)blockIdx.y * 128;
  gemm128_mainloop(ob, wo, 1024, brow, bcol, As, Bs, acc);

  const int wave = threadIdx.x >> 6, lane = threadIdx.x & 63;
  const int wr = wave >> 1, wc = wave & 1, lr = lane & 15, lg = lane >> 4;
#pragma unroll
  for (int i = 0; i < 4; ++i)
#pragma unroll
    for (int j = 0; j < 4; ++j)
#pragma unroll
      for (int r = 0; r < 4; ++r) {
        int m = (int)brow + wr * 64 + i * 16 + lg * 4 + r;
        int n = (int)bcol + wc * 64 + j * 16 + lr;
        out[(long)m * 1024 + n] = acc[i][j][r] + bo[n];
      }
}

// ---------------------------------------------------------------------------
// Flash attention v2 (causal, balanced, swapped-QK^T).
// Grid: (16, B*H). Block = 4 waves; wave w owns q rows [qt*64+w*16, +16).
// Block pr processes q-tiles pr and 31-pr  => 33 kv-iters for every block.
// S^T = mfma(K,Q): lane holds S[kv=kv0+16nt+4lg+r][q=q0+lr] -> row softmax is
// 14 in-lane VALU ops + shfl_xor(16/32). P staged per-wave in LDS [q][72].
// ---------------------------------------------------------------------------
struct KFrag {
  short8 f[4][2];
};

__device__ __forceinline__ void load_kfrag(KFrag& kf, const unsigned short* __restrict__ Kp,
                                           int kv0, int lr, int lg) {
#pragma unroll
  for (int nt = 0; nt < 4; ++nt) {
    const unsigned short* kp = Kp + (kv0 + nt * 16 + lr) * 64 + lg * 8;
    kf.f[nt][0] = *(const short8*)kp;
    kf.f[nt][1] = *(const short8*)(kp + 32);
  }
}

__device__ __forceinline__ void attn_kv_step(
    KFrag& kf, const short8& qf0, const short8& qf1,
    const unsigned short* __restrict__ Kp, const unsigned short* __restrict__ Vt,
    unsigned short* __restrict__ PTw, int kv0, int q0, int lr, int lg,
    bool diag, bool prefetch, float& m_i, float& l_i, floatx4 accO[4]) {
  floatx4 zero = {0.f, 0.f, 0.f, 0.f};
  floatx4 s[4];
#pragma unroll
  for (int nt = 0; nt < 4; ++nt) {
    floatx4 a = zero;
    a = __builtin_amdgcn_mfma_f32_16x16x32_bf16(kf.f[nt][0], qf0, a, 0, 0, 0);
    a = __builtin_amdgcn_mfma_f32_16x16x32_bf16(kf.f[nt][1], qf1, a, 0, 0, 0);
    s[nt] = a;
  }
  // kf registers are dead now: prefetch next kv tile (latency hidden by
  // softmax + PV below).
  if (prefetch) load_kfrag(kf, Kp, kv0 + 64, lr, lg);

  const int q = q0 + lr;
  if (diag) {
#pragma unroll
    for (int nt = 0; nt < 4; ++nt)
#pragma unroll
      for (int r = 0; r < 4; ++r) {
        int kvi = kv0 + nt * 16 + lg * 4 + r;
        s[nt][r] = (kvi <= q) ? s[nt][r] * 0.125f : -1e30f;
      }
  } else {
#pragma unroll
    for (int nt = 0; nt < 4; ++nt)
#pragma unroll
      for (int r = 0; r < 4; ++r) s[nt][r] *= 0.125f;
  }
  // row max: all 16 in-lane values belong to q = q0+lr
  float mnt[4];
#pragma unroll
  for (int nt = 0; nt < 4; ++nt)
    mnt[nt] = fmaxf(fmaxf(s[nt][0], s[nt][1]), fmaxf(s[nt][2], s[nt][3]));
  float pmax = fmaxf(fmaxf(mnt[0], mnt[1]), fmaxf(mnt[2], mnt[3]));
  pmax = fmaxf(pmax, __shfl_xor(pmax, 16));
  pmax = fmaxf(pmax, __shfl_xor(pmax, 32));
  float mnew = fmaxf(m_i, pmax);
  float scl = exp2f((m_i - mnew) * LOG2E);
  m_i = mnew;

  float rs = 0.f;
#pragma unroll
  for (int nt = 0; nt < 4; ++nt) {
    short4v pk;
    float ps = 0.f;
#pragma unroll
    for (int r = 0; r < 4; ++r) {
      float p = exp2f((s[nt][r] - mnew) * LOG2E);
      ps += p;
      pk[r] = (short)f2bf(p);
    }
    rs += ps;
    *(short4v*)(PTw + lr * 72 + nt * 16 + lg * 4) = pk;
  }
  rs += __shfl_xor(rs, 16);
  rs += __shfl_xor(rs, 32);
  l_i = l_i * scl + rs;

  // rescale accO: its rows are q = q0 + 4*lg + r -> broadcast scl from lane 4*lg+r
#pragma unroll
  for (int r = 0; r < 4; ++r) {
    float so = __shfl(scl, lg * 4 + r);
#pragma unroll
    for (int dt = 0; dt < 4; ++dt) accO[dt][r] *= so;
  }

  // PV: A = P from LDS (b128), B = V rows from Vt (global, L2-resident)
#pragma unroll
  for (int kk = 0; kk < 2; ++kk) {
    short8 pf = *(const short8*)(PTw + lr * 72 + kk * 32 + lg * 8);
#pragma unroll
    for (int dt = 0; dt < 4; ++dt) {
      short8 vf = *(const short8*)(Vt + (long)(dt * 16 + lr) * 2048 + kv0 + kk * 32 + lg * 8);
      accO[dt] = __builtin_amdgcn_mfma_f32_16x16x32_bf16(pf, vf, accO[dt], 0, 0, 0);
    }
  }
}

__global__ __launch_bounds__(256) void attn_fwd(
    const unsigned short* __restrict__ qb, const unsigned short* __restrict__ kb,
    const unsigned short* __restrict__ vtb, unsigned short* __restrict__ ob) {
  const int pr = blockIdx.x;  // 0..15
  const int bh = blockIdx.y;
  const int wave = threadIdx.x >> 6, lane = threadIdx.x & 63;
  const int lr = lane & 15, lg = lane >> 4;
  const unsigned short* Q = qb + (long)bh * 2048 * 64;
  const unsigned short* Kp = kb + (long)bh * 2048 * 64;
  const unsigned short* Vt = vtb + (long)bh * 64 * 2048;
  const int b = bh >> 4, h = bh & 15;

  __shared__ unsigned short PT[4][16 * 72];
  unsigned short* PTw = PT[wave];

  floatx4 zero = {0.f, 0.f, 0.f, 0.f};

#pragma unroll 1
  for (int half = 0; half < 2; ++half) {
    const int qt = half ? (31 - pr) : pr;
    const int q0 = qt * 64 + wave * 16;
    const int nkv = qt + 1;

    short8 qf0 = *(const short8*)(Q + (q0 + lr) * 64 + lg * 8);
    short8 qf1 = *(const short8*)(Q + (q0 + lr) * 64 + 32 + lg * 8);

    floatx4 accO[4];
#pragma unroll
    for (int dt = 0; dt < 4; ++dt) accO[dt] = zero;
    float m_i = -1e30f, l_i = 0.f;

    KFrag kf;
    load_kfrag(kf, Kp, 0, lr, lg);
#pragma unroll 1
    for (int kv = 0; kv < nkv; ++kv) {
      attn_kv_step(kf, qf0, qf1, Kp, Vt, PTw, kv * 64, q0, lr, lg,
                   kv == qt, kv + 1 < nkv, m_i, l_i, accO);
    }

    float linv = 1.f / l_i;
#pragma unroll
    for (int r = 0; r < 4; ++r) {
      float io = __shfl(linv, lg * 4 + r);
      int t = q0 + 4 * lg + r;
#pragma unroll
      for (int dt = 0; dt < 4; ++dt)
        ob[((long)b * 2048 + t) * 1024 + h * 64 + dt * 16 + lr] =
            f2bf(accO[dt][r] * io);
    }
  }
}

// ---------------------------------------------------------------------------
extern "C" void kernel_launch(void* const* d_in, const int* in_sizes, int n_in,
                              void* d_out, int out_size, void* d_ws, size_t ws_size,
                              hipStream_t stream) {
  const float* x = (const float*)d_in[0];
  const float* bq = (const float*)d_in[2];
  const float* bk = (const float*)d_in[4];
  const float* bv = (const float*)d_in[6];
  const float* bo = (const float*)d_in[8];
  float* out = (float*)d_out;

  char* ws = (char*)d_ws;
  unsigned short* xb = (unsigned short*)(ws);                  // 16 MB  [8192][1024]
  unsigned short* wqkv = (unsigned short*)(ws + (16l << 20));  // 6 MB   [3072][1024]
  unsigned short* wob = (unsigned short*)(ws + (22l << 20));   // 2 MB   [1024][1024]
  unsigned short* qb = (unsigned short*)(ws + (24l << 20));    // 16 MB  [64][2048][64]
  unsigned short* kb = (unsigned short*)(ws + (40l << 20));    // 16 MB  [64][2048][64]
  unsigned short* vtb = (unsigned short*)(ws + (56l << 20));   // 16 MB  [64][64][2048]
  unsigned short* ob = (unsigned short*)(ws + (72l << 20));    // 16 MB  [8192][1024]

  f2b_kernel<<<2097152 / 256, 256, 0, stream>>>(x, xb, 2097152);
  f2b_kernel<<<262144 / 256, 256, 0, stream>>>((const float*)d_in[1], wqkv, 262144);
  f2b_kernel<<<262144 / 256, 256, 0, stream>>>((const float*)d_in[3], wqkv + (1l << 20), 262144);
  f2b_kernel<<<262144 / 256, 256, 0, stream>>>((const float*)d_in[5], wqkv + (2l << 20), 262144);
  f2b_kernel<<<262144 / 256, 256, 0, stream>>>((const float*)d_in[7], wob, 262144);

  qkv_gemm<<<dim3(64, 24), 256, 0, stream>>>(xb, wqkv, bq, bk, bv, qb, kb, vtb);
  attn_fwd<<<dim3(16, 64), 256, 0, stream>>>(qb, kb, vtb, ob);
  out_gemm<<<dim3(64, 8), 256, 0, stream>>>(ob, wob, bo, out);
}

// Round 3
// 230.041 us; speedup vs baseline: 2.4711x; 1.5940x over previous
//
#include <hip/hip_runtime.h>
#include <stdint.h>

typedef __attribute__((ext_vector_type(8))) short short8;
typedef __attribute__((ext_vector_type(4))) short short4v;
typedef __attribute__((ext_vector_type(4))) float floatx4;

#define LOG2E 1.44269504088896f

__device__ __forceinline__ unsigned short f2bf(float f) {
  unsigned int u = __float_as_uint(f);
  unsigned int r = (u + 0x7FFFu + ((u >> 16) & 1u)) >> 16;  // RNE
  return (unsigned short)r;
}

__device__ __forceinline__ unsigned int cvt_pk_bf16(float lo, float hi) {
  unsigned int r;
  asm("v_cvt_pk_bf16_f32 %0, %1, %2" : "=v"(r) : "v"(lo), "v"(hi));
  return r;
}

__device__ __forceinline__ void async_copy16(void* lds, const void* g) {
  __builtin_amdgcn_global_load_lds(
      (const __attribute__((address_space(1))) unsigned int*)g,
      (__attribute__((address_space(3))) unsigned int*)lds, 16, 0, 0);
}

// ---------------------------------------------------------------------------
// fp32 -> bf16 conversion
// ---------------------------------------------------------------------------
__global__ __launch_bounds__(256) void f2b_kernel(const float* __restrict__ in,
                                                  unsigned short* __restrict__ out,
                                                  int n4) {
  int i = blockIdx.x * 256 + threadIdx.x;
  if (i >= n4) return;
  float4 v = ((const float4*)in)[i];
  short4v o;
  o[0] = (short)f2bf(v.x);
  o[1] = (short)f2bf(v.y);
  o[2] = (short)f2bf(v.z);
  o[3] = (short)f2bf(v.w);
  *(short4v*)(out + (long)i * 4) = o;
}

// ---------------------------------------------------------------------------
// m97-structure GEMM mainloop: C[128x128] = A[128xK] * Bt[128xK]^T
// ---------------------------------------------------------------------------
__device__ __forceinline__ void gemm128_mainloop(
    const unsigned short* __restrict__ A, const unsigned short* __restrict__ Bt,
    int K, long brow, long bcol, unsigned short* As, unsigned short* Bs,
    floatx4 acc[4][4]) {
  const int tid = threadIdx.x;
  const int wave = tid >> 6;
  const int lane = tid & 63;
  const int wr = wave >> 1, wc = wave & 1;
  const int lr = lane & 15, lg = lane >> 4;

  const unsigned short* ga = A + (brow + (tid >> 2)) * (long)K + (tid & 3) * 8;
  const unsigned short* gb = Bt + (bcol + (tid >> 2)) * (long)K + (tid & 3) * 8;
  unsigned short* lA = As + wave * 512;
  unsigned short* lB = Bs + wave * 512;
  const int a_off = (wr * 64 + lr) * 32 + lg * 8;
  const int b_off = (wc * 64 + lr) * 32 + lg * 8;

  for (int kt = 0; kt < K; kt += 32) {
    __syncthreads();
    async_copy16(lA, ga);
    async_copy16(lA + 2048, ga + (long)64 * K);
    async_copy16(lB, gb);
    async_copy16(lB + 2048, gb + (long)64 * K);
    ga += 32;
    gb += 32;
    __syncthreads();
    short8 af[4], bf[4];
#pragma unroll
    for (int i = 0; i < 4; ++i) {
      af[i] = *(const short8*)(As + a_off + i * 512);
      bf[i] = *(const short8*)(Bs + b_off + i * 512);
    }
#pragma unroll
    for (int i = 0; i < 4; ++i)
#pragma unroll
      for (int j = 0; j < 4; ++j)
        acc[i][j] = __builtin_amdgcn_mfma_f32_16x16x32_bf16(af[i], bf[j], acc[i][j], 0, 0, 0);
  }
}

// ---------------------------------------------------------------------------
// QKV projection
// ---------------------------------------------------------------------------
__global__ __launch_bounds__(256) void qkv_gemm(
    const unsigned short* __restrict__ xb, const unsigned short* __restrict__ wqkv,
    const float* __restrict__ bq, const float* __restrict__ bk,
    const float* __restrict__ bv, unsigned short* __restrict__ q_out,
    unsigned short* __restrict__ k_out, unsigned short* __restrict__ vt_out) {
  __shared__ unsigned short As[128 * 32];
  __shared__ unsigned short Bs[128 * 32];
  floatx4 zero = {0.f, 0.f, 0.f, 0.f};
  floatx4 acc[4][4];
#pragma unroll
  for (int i = 0; i < 4; ++i)
#pragma unroll
    for (int j = 0; j < 4; ++j) acc[i][j] = zero;

  long brow = (long)blockIdx.x * 128;
  long bcol = (long)blockIdx.y * 128;
  gemm128_mainloop(xb, wqkv, 1024, brow, bcol, As, Bs, acc);

  const int wave = threadIdx.x >> 6, lane = threadIdx.x & 63;
  const int wr = wave >> 1, wc = wave & 1, lr = lane & 15, lg = lane >> 4;
  const int kind = (int)(bcol >> 10);
  const float* bias = (kind == 0) ? bq : (kind == 1 ? bk : bv);
#pragma unroll
  for (int i = 0; i < 4; ++i)
#pragma unroll
    for (int j = 0; j < 4; ++j)
#pragma unroll
      for (int r = 0; r < 4; ++r) {
        int m = (int)brow + wr * 64 + i * 16 + lg * 4 + r;
        int n = (int)bcol + wc * 64 + j * 16 + lr;
        int f = n & 1023;
        float v = acc[i][j][r] + bias[f];
        unsigned short o = f2bf(v);
        int h = f >> 6, d = f & 63;
        int b = m >> 11, t = m & 2047;
        long bh = (long)(b * 16 + h);
        if (kind == 0)
          q_out[(bh * 2048 + t) * 64 + d] = o;
        else if (kind == 1)
          k_out[(bh * 2048 + t) * 64 + d] = o;
        else
          vt_out[(bh * 64 + d) * 2048 + t] = o;
      }
}

// ---------------------------------------------------------------------------
// Output projection
// ---------------------------------------------------------------------------
__global__ __launch_bounds__(256) void out_gemm(
    const unsigned short* __restrict__ ob, const unsigned short* __restrict__ wo,
    const float* __restrict__ bo, float* __restrict__ out) {
  __shared__ unsigned short As[128 * 32];
  __shared__ unsigned short Bs[128 * 32];
  floatx4 zero = {0.f, 0.f, 0.f, 0.f};
  floatx4 acc[4][4];
#pragma unroll
  for (int i = 0; i < 4; ++i)
#pragma unroll
    for (int j = 0; j < 4; ++j) acc[i][j] = zero;

  long brow = (long)blockIdx.x * 128;
  long bcol = (long)blockIdx.y * 128;
  gemm128_mainloop(ob, wo, 1024, brow, bcol, As, Bs, acc);

  const int wave = threadIdx.x >> 6, lane = threadIdx.x & 63;
  const int wr = wave >> 1, wc = wave & 1, lr = lane & 15, lg = lane >> 4;
#pragma unroll
  for (int i = 0; i < 4; ++i)
#pragma unroll
    for (int j = 0; j < 4; ++j)
#pragma unroll
      for (int r = 0; r < 4; ++r) {
        int m = (int)brow + wr * 64 + i * 16 + lg * 4 + r;
        int n = (int)bcol + wc * 64 + j * 16 + lr;
        out[(long)m * 1024 + n] = acc[i][j][r] + bo[n];
      }
}

// ---------------------------------------------------------------------------
// Flash attention v3: LDS-staged K/V (double-buffered, swizzled), XCD-local
// blocks, swapped-QK^T in-lane softmax, cvt_pk P packing.
//
// LDS tile layout (K and V): 64 rows x 8 chunks of 16B; chunk c of row r
// stored at position c ^ (r&7)  (achieved by pre-swizzling the GLOBAL source
// address fed to global_load_lds; LDS dest stays linear).
// P buffer per wave: rows q=lr (128B), kv-word w (u32, 32/row) stored at
// chunk (w>>2)^(lr&7), word w&3.
// ---------------------------------------------------------------------------
__device__ __forceinline__ void stage_kv(char* __restrict__ Kb, char* __restrict__ Vb,
                                         const char* __restrict__ Kp,
                                         const char* __restrict__ Vt, int kv0,
                                         int tid) {
  const int wave = tid >> 6;
#pragma unroll
  for (int j = 0; j < 2; ++j) {
    int d = j * 256 + tid;  // chunk id 0..511
    int row = d >> 3, cc = d & 7;
    int gc = cc ^ (row & 7);
    const char* gk = Kp + (size_t)kv0 * 128 + row * 128 + gc * 16;
    async_copy16(Kb + (j * 256 + wave * 64) * 16, gk);
    const char* gv = Vt + (size_t)row * 4096 + (size_t)kv0 * 2 + gc * 16;
    async_copy16(Vb + (j * 256 + wave * 64) * 16, gv);
  }
}

__device__ __forceinline__ void attn_step(
    const char* __restrict__ Kb, const char* __restrict__ Vb,
    char* __restrict__ PTw, const short8& qf0, const short8& qf1,
    int kv0, int q0, int lr, int lg, bool diag,
    float& m_i, float& l_i, floatx4 accO[4]) {
  floatx4 zero = {0.f, 0.f, 0.f, 0.f};
  const int x7 = lr & 7;
  floatx4 s[4];
  __builtin_amdgcn_s_setprio(1);
#pragma unroll
  for (int nt = 0; nt < 4; ++nt) {
    const char* kr = Kb + (nt * 16 + lr) * 128;
    short8 kf0 = *(const short8*)(kr + ((lg ^ x7) * 16));
    short8 kf1 = *(const short8*)(kr + (((4 + lg) ^ x7) * 16));
    floatx4 a = zero;
    a = __builtin_amdgcn_mfma_f32_16x16x32_bf16(kf0, qf0, a, 0, 0, 0);
    a = __builtin_amdgcn_mfma_f32_16x16x32_bf16(kf1, qf1, a, 0, 0, 0);
    s[nt] = a;
  }
  __builtin_amdgcn_s_setprio(0);

  const int q = q0 + lr;
  if (diag) {
#pragma unroll
    for (int nt = 0; nt < 4; ++nt)
#pragma unroll
      for (int r = 0; r < 4; ++r) {
        int kvi = kv0 + nt * 16 + lg * 4 + r;
        s[nt][r] = (kvi <= q) ? s[nt][r] * 0.125f : -1e30f;
      }
  } else {
#pragma unroll
    for (int nt = 0; nt < 4; ++nt)
#pragma unroll
      for (int r = 0; r < 4; ++r) s[nt][r] *= 0.125f;
  }
  // row max (16 in-lane values all belong to q = q0+lr)
  float mnt[4];
#pragma unroll
  for (int nt = 0; nt < 4; ++nt)
    mnt[nt] = fmaxf(fmaxf(s[nt][0], s[nt][1]), fmaxf(s[nt][2], s[nt][3]));
  float pmax = fmaxf(fmaxf(mnt[0], mnt[1]), fmaxf(mnt[2], mnt[3]));
  pmax = fmaxf(pmax, __shfl_xor(pmax, 16));
  pmax = fmaxf(pmax, __shfl_xor(pmax, 32));
  float mnew = fmaxf(m_i, pmax);
  float scl = exp2f((m_i - mnew) * LOG2E);
  m_i = mnew;

  float rs = 0.f;
#pragma unroll
  for (int nt = 0; nt < 4; ++nt) {
    float p0 = exp2f((s[nt][0] - mnew) * LOG2E);
    float p1 = exp2f((s[nt][1] - mnew) * LOG2E);
    float p2 = exp2f((s[nt][2] - mnew) * LOG2E);
    float p3 = exp2f((s[nt][3] - mnew) * LOG2E);
    rs += (p0 + p1) + (p2 + p3);
    uint2 wv;
    wv.x = cvt_pk_bf16(p0, p1);
    wv.y = cvt_pk_bf16(p2, p3);
    // kv-words w = 8nt+2lg (+1): chunk 2nt+(lg>>1) xor (lr&7), byte (2lg&3)*4
    *(uint2*)(PTw + lr * 128 + (((2 * nt + (lg >> 1)) ^ x7) * 16) + ((2 * lg) & 3) * 4) = wv;
  }
  rs += __shfl_xor(rs, 16);
  rs += __shfl_xor(rs, 32);
  l_i = l_i * scl + rs;

  // rescale accO (rows q = q0 + 4*lg + r)
#pragma unroll
  for (int r = 0; r < 4; ++r) {
    float so = __shfl(scl, lg * 4 + r);
#pragma unroll
    for (int dt = 0; dt < 4; ++dt) accO[dt][r] *= so;
  }

  __builtin_amdgcn_s_setprio(1);
#pragma unroll
  for (int kk = 0; kk < 2; ++kk) {
    short8 pf = *(const short8*)(PTw + lr * 128 + (((4 * kk + lg) ^ x7) * 16));
#pragma unroll
    for (int dt = 0; dt < 4; ++dt) {
      short8 vf = *(const short8*)(Vb + (dt * 16 + lr) * 128 + (((4 * kk + lg) ^ x7) * 16));
      accO[dt] = __builtin_amdgcn_mfma_f32_16x16x32_bf16(pf, vf, accO[dt], 0, 0, 0);
    }
  }
  __builtin_amdgcn_s_setprio(0);
}

__global__ __launch_bounds__(256) void attn_fwd(
    const unsigned short* __restrict__ qb, const unsigned short* __restrict__ kb,
    const unsigned short* __restrict__ vtb, unsigned short* __restrict__ ob) {
  __shared__ __align__(16) char Kbuf[2][8192];
  __shared__ __align__(16) char Vbuf[2][8192];
  __shared__ __align__(16) char PTbuf[4][2048];

  // XCD-local remap: all 16 q-tile blocks of one bh land on one XCD
  // (assumes round-robin xcd = linear_wg_id % 8).
  const int F = blockIdx.y * 16 + blockIdx.x;  // 0..1023
  const int c = F & 7, t = F >> 3;
  const int bh = c * 8 + (t >> 4);
  const int pr = t & 15;

  const int tid = threadIdx.x;
  const int wave = tid >> 6, lane = tid & 63;
  const int lr = lane & 15, lg = lane >> 4;
  const unsigned short* Q = qb + (long)bh * 2048 * 64;
  const char* Kp = (const char*)(kb + (long)bh * 2048 * 64);
  const char* Vt = (const char*)(vtb + (long)bh * 64 * 2048);
  const int b = bh >> 4, h = bh & 15;
  char* PTw = PTbuf[wave];

  floatx4 zero = {0.f, 0.f, 0.f, 0.f};

#pragma unroll 1
  for (int half = 0; half < 2; ++half) {
    const int qt = half ? (31 - pr) : pr;
    const int q0 = qt * 64 + wave * 16;
    const int nkv = qt + 1;

    short8 qf0 = *(const short8*)(Q + (q0 + lr) * 64 + lg * 8);
    short8 qf1 = *(const short8*)(Q + (q0 + lr) * 64 + 32 + lg * 8);

    floatx4 accO[4];
#pragma unroll
    for (int dt = 0; dt < 4; ++dt) accO[dt] = zero;
    float m_i = -1e30f, l_i = 0.f;

    stage_kv(Kbuf[0], Vbuf[0], Kp, Vt, 0, tid);
    __syncthreads();
#pragma unroll 1
    for (int kv = 0; kv < nkv; ++kv) {
      if (kv + 1 < nkv)
        stage_kv(Kbuf[(kv + 1) & 1], Vbuf[(kv + 1) & 1], Kp, Vt, (kv + 1) * 64, tid);
      attn_step(Kbuf[kv & 1], Vbuf[kv & 1], PTw, qf0, qf1, kv * 64, q0, lr, lg,
                kv == qt, m_i, l_i, accO);
      __syncthreads();
    }

    float linv = 1.f / l_i;
#pragma unroll
    for (int r = 0; r < 4; ++r) {
      float io = __shfl(linv, lg * 4 + r);
      int tq = q0 + 4 * lg + r;
#pragma unroll
      for (int dt = 0; dt < 4; ++dt)
        ob[((long)b * 2048 + tq) * 1024 + h * 64 + dt * 16 + lr] =
            f2bf(accO[dt][r] * io);
    }
  }
}

// ---------------------------------------------------------------------------
extern "C" void kernel_launch(void* const* d_in, const int* in_sizes, int n_in,
                              void* d_out, int out_size, void* d_ws, size_t ws_size,
                              hipStream_t stream) {
  const float* x = (const float*)d_in[0];
  const float* bq = (const float*)d_in[2];
  const float* bk = (const float*)d_in[4];
  const float* bv = (const float*)d_in[6];
  const float* bo = (const float*)d_in[8];
  float* out = (float*)d_out;

  char* ws = (char*)d_ws;
  unsigned short* xb = (unsigned short*)(ws);                  // 16 MB  [8192][1024]
  unsigned short* wqkv = (unsigned short*)(ws + (16l << 20));  // 6 MB   [3072][1024]
  unsigned short* wob = (unsigned short*)(ws + (22l << 20));   // 2 MB   [1024][1024]
  unsigned short* qb = (unsigned short*)(ws + (24l << 20));    // 16 MB  [64][2048][64]
  unsigned short* kb = (unsigned short*)(ws + (40l << 20));    // 16 MB  [64][2048][64]
  unsigned short* vtb = (unsigned short*)(ws + (56l << 20));   // 16 MB  [64][64][2048]
  unsigned short* ob = (unsigned short*)(ws + (72l << 20));    // 16 MB  [8192][1024]

  f2b_kernel<<<2097152 / 256, 256, 0, stream>>>(x, xb, 2097152);
  f2b_kernel<<<262144 / 256, 256, 0, stream>>>((const float*)d_in[1], wqkv, 262144);
  f2b_kernel<<<262144 / 256, 256, 0, stream>>>((const float*)d_in[3], wqkv + (1l << 20), 262144);
  f2b_kernel<<<262144 / 256, 256, 0, stream>>>((const float*)d_in[5], wqkv + (2l << 20), 262144);
  f2b_kernel<<<262144 / 256, 256, 0, stream>>>((const float*)d_in[7], wob, 262144);

  qkv_gemm<<<dim3(64, 24), 256, 0, stream>>>(xb, wqkv, bq, bk, bv, qb, kb, vtb);
  attn_fwd<<<dim3(16, 64), 256, 0, stream>>>(qb, kb, vtb, ob);
  out_gemm<<<dim3(64, 8), 256, 0, stream>>>(ob, wob, bo, out);
}

// Round 4
// 197.179 us; speedup vs baseline: 2.8829x; 1.1667x over previous
//
#include <hip/hip_runtime.h>
#include <stdint.h>

typedef __attribute__((ext_vector_type(8))) short short8;
typedef __attribute__((ext_vector_type(4))) short short4v;
typedef __attribute__((ext_vector_type(4))) float floatx4;

#define QSCALE 0.1803368801111f /* 0.125 * log2(e): S in log2 units */

__device__ __forceinline__ unsigned short f2bf(float f) {
  unsigned int u = __float_as_uint(f);
  unsigned int r = (u + 0x7FFFu + ((u >> 16) & 1u)) >> 16;  // RNE
  return (unsigned short)r;
}

__device__ __forceinline__ unsigned int cvt_pk_bf16(float lo, float hi) {
  unsigned int r;
  asm("v_cvt_pk_bf16_f32 %0, %1, %2" : "=v"(r) : "v"(lo), "v"(hi));
  return r;
}

__device__ __forceinline__ void async_copy16(void* lds, const void* g) {
  __builtin_amdgcn_global_load_lds(
      (const __attribute__((address_space(1))) unsigned int*)g,
      (__attribute__((address_space(3))) unsigned int*)lds, 16, 0, 0);
}

// ---------------------------------------------------------------------------
// fp32 -> bf16 conversion
// ---------------------------------------------------------------------------
__global__ __launch_bounds__(256) void f2b_kernel(const float* __restrict__ in,
                                                  unsigned short* __restrict__ out,
                                                  int n4) {
  int i = blockIdx.x * 256 + threadIdx.x;
  if (i >= n4) return;
  float4 v = ((const float4*)in)[i];
  short4v o;
  o[0] = (short)f2bf(v.x);
  o[1] = (short)f2bf(v.y);
  o[2] = (short)f2bf(v.z);
  o[3] = (short)f2bf(v.w);
  *(short4v*)(out + (long)i * 4) = o;
}

// ---------------------------------------------------------------------------
// m97-structure GEMM mainloop: C[128x128] = A[128xK] * Bt[128xK]^T
// ---------------------------------------------------------------------------
__device__ __forceinline__ void gemm128_mainloop(
    const unsigned short* __restrict__ A, const unsigned short* __restrict__ Bt,
    int K, long brow, long bcol, unsigned short* As, unsigned short* Bs,
    floatx4 acc[4][4]) {
  const int tid = threadIdx.x;
  const int wave = tid >> 6;
  const int lane = tid & 63;
  const int wr = wave >> 1, wc = wave & 1;
  const int lr = lane & 15, lg = lane >> 4;

  const unsigned short* ga = A + (brow + (tid >> 2)) * (long)K + (tid & 3) * 8;
  const unsigned short* gb = Bt + (bcol + (tid >> 2)) * (long)K + (tid & 3) * 8;
  unsigned short* lA = As + wave * 512;
  unsigned short* lB = Bs + wave * 512;
  const int a_off = (wr * 64 + lr) * 32 + lg * 8;
  const int b_off = (wc * 64 + lr) * 32 + lg * 8;

  for (int kt = 0; kt < K; kt += 32) {
    __syncthreads();
    async_copy16(lA, ga);
    async_copy16(lA + 2048, ga + (long)64 * K);
    async_copy16(lB, gb);
    async_copy16(lB + 2048, gb + (long)64 * K);
    ga += 32;
    gb += 32;
    __syncthreads();
    short8 af[4], bf[4];
#pragma unroll
    for (int i = 0; i < 4; ++i) {
      af[i] = *(const short8*)(As + a_off + i * 512);
      bf[i] = *(const short8*)(Bs + b_off + i * 512);
    }
#pragma unroll
    for (int i = 0; i < 4; ++i)
#pragma unroll
      for (int j = 0; j < 4; ++j)
        acc[i][j] = __builtin_amdgcn_mfma_f32_16x16x32_bf16(af[i], bf[j], acc[i][j], 0, 0, 0);
  }
}

// ---------------------------------------------------------------------------
// QKV projection. Q is written PRE-SCALED by 0.125*log2(e) so attention
// scores come out of the QK^T MFMA already in log2 units.
// ---------------------------------------------------------------------------
__global__ __launch_bounds__(256) void qkv_gemm(
    const unsigned short* __restrict__ xb, const unsigned short* __restrict__ wqkv,
    const float* __restrict__ bq, const float* __restrict__ bk,
    const float* __restrict__ bv, unsigned short* __restrict__ q_out,
    unsigned short* __restrict__ k_out, unsigned short* __restrict__ vt_out) {
  __shared__ unsigned short As[128 * 32];
  __shared__ unsigned short Bs[128 * 32];
  floatx4 zero = {0.f, 0.f, 0.f, 0.f};
  floatx4 acc[4][4];
#pragma unroll
  for (int i = 0; i < 4; ++i)
#pragma unroll
    for (int j = 0; j < 4; ++j) acc[i][j] = zero;

  long brow = (long)blockIdx.x * 128;
  long bcol = (long)blockIdx.y * 128;
  gemm128_mainloop(xb, wqkv, 1024, brow, bcol, As, Bs, acc);

  const int wave = threadIdx.x >> 6, lane = threadIdx.x & 63;
  const int wr = wave >> 1, wc = wave & 1, lr = lane & 15, lg = lane >> 4;
  const int kind = (int)(bcol >> 10);
  const float* bias = (kind == 0) ? bq : (kind == 1 ? bk : bv);
#pragma unroll
  for (int i = 0; i < 4; ++i)
#pragma unroll
    for (int j = 0; j < 4; ++j)
#pragma unroll
      for (int r = 0; r < 4; ++r) {
        int m = (int)brow + wr * 64 + i * 16 + lg * 4 + r;
        int n = (int)bcol + wc * 64 + j * 16 + lr;
        int f = n & 1023;
        float v = acc[i][j][r] + bias[f];
        if (kind == 0) v *= QSCALE;
        unsigned short o = f2bf(v);
        int h = f >> 6, d = f & 63;
        int b = m >> 11, t = m & 2047;
        long bh = (long)(b * 16 + h);
        if (kind == 0)
          q_out[(bh * 2048 + t) * 64 + d] = o;
        else if (kind == 1)
          k_out[(bh * 2048 + t) * 64 + d] = o;
        else
          vt_out[(bh * 64 + d) * 2048 + t] = o;
      }
}

// ---------------------------------------------------------------------------
// Output projection
// ---------------------------------------------------------------------------
__global__ __launch_bounds__(256) void out_gemm(
    const unsigned short* __restrict__ ob, const unsigned short* __restrict__ wo,
    const float* __restrict__ bo, float* __restrict__ out) {
  __shared__ unsigned short As[128 * 32];
  __shared__ unsigned short Bs[128 * 32];
  floatx4 zero = {0.f, 0.f, 0.f, 0.f};
  floatx4 acc[4][4];
#pragma unroll
  for (int i = 0; i < 4; ++i)
#pragma unroll
    for (int j = 0; j < 4; ++j) acc[i][j] = zero;

  long brow = (long)blockIdx.x * 128;
  long bcol = (long)blockIdx.y * 128;
  gemm128_mainloop(ob, wo, 1024, brow, bcol, As, Bs, acc);

  const int wave = threadIdx.x >> 6, lane = threadIdx.x & 63;
  const int wr = wave >> 1, wc = wave & 1, lr = lane & 15, lg = lane >> 4;
#pragma unroll
  for (int i = 0; i < 4; ++i)
#pragma unroll
    for (int j = 0; j < 4; ++j)
#pragma unroll
      for (int r = 0; r < 4; ++r) {
        int m = (int)brow + wr * 64 + i * 16 + lg * 4 + r;
        int n = (int)bcol + wc * 64 + j * 16 + lr;
        out[(long)m * 1024 + n] = acc[i][j][r] + bo[n];
      }
}

// ---------------------------------------------------------------------------
// Flash attention v4: LDS-staged K/V (double-buffered, swizzled), XCD-local,
// swapped-QK^T, log2-domain softmax (Q pre-scaled), defer-max (THR=8 nats),
// per-lane partial l (no cross-lane ops in the common path).
// ---------------------------------------------------------------------------
__device__ __forceinline__ void stage_kv(char* __restrict__ Kb, char* __restrict__ Vb,
                                         const char* __restrict__ Kp,
                                         const char* __restrict__ Vt, int kv0,
                                         int tid) {
  const int wave = tid >> 6;
#pragma unroll
  for (int j = 0; j < 2; ++j) {
    int d = j * 256 + tid;  // chunk id 0..511
    int row = d >> 3, cc = d & 7;
    int gc = cc ^ (row & 7);
    const char* gk = Kp + (size_t)kv0 * 128 + row * 128 + gc * 16;
    async_copy16(Kb + (j * 256 + wave * 64) * 16, gk);
    const char* gv = Vt + (size_t)row * 4096 + (size_t)kv0 * 2 + gc * 16;
    async_copy16(Vb + (j * 256 + wave * 64) * 16, gv);
  }
}

__device__ __forceinline__ void attn_step(
    const char* __restrict__ Kb, const char* __restrict__ Vb,
    char* __restrict__ PTw, const short8& qf0, const short8& qf1,
    int kv0, int q0, int lr, int lg, bool diag,
    float& m_i, float& l_i, floatx4 accO[4]) {
  floatx4 zero = {0.f, 0.f, 0.f, 0.f};
  const int x7 = lr & 7;
  floatx4 s[4];
  __builtin_amdgcn_s_setprio(1);
#pragma unroll
  for (int nt = 0; nt < 4; ++nt) {
    const char* kr = Kb + (nt * 16 + lr) * 128;
    short8 kf0 = *(const short8*)(kr + ((lg ^ x7) * 16));
    short8 kf1 = *(const short8*)(kr + (((4 + lg) ^ x7) * 16));
    floatx4 a = zero;
    a = __builtin_amdgcn_mfma_f32_16x16x32_bf16(kf0, qf0, a, 0, 0, 0);
    a = __builtin_amdgcn_mfma_f32_16x16x32_bf16(kf1, qf1, a, 0, 0, 0);
    s[nt] = a;
  }
  __builtin_amdgcn_s_setprio(0);

  // causal mask (diagonal tile only); S already in log2 units
  if (diag) {
    const int q = q0 + lr;
#pragma unroll
    for (int nt = 0; nt < 4; ++nt)
#pragma unroll
      for (int r = 0; r < 4; ++r) {
        int kvi = kv0 + nt * 16 + lg * 4 + r;
        if (kvi > q) s[nt][r] = -1e30f;
      }
  }
  // in-lane row max (16 values, all same q = q0+lr)
  float mnt[4];
#pragma unroll
  for (int nt = 0; nt < 4; ++nt)
    mnt[nt] = fmaxf(fmaxf(s[nt][0], s[nt][1]), fmaxf(s[nt][2], s[nt][3]));
  float pmax = fmaxf(fmaxf(mnt[0], mnt[1]), fmaxf(mnt[2], mnt[3]));

  // defer-max: only rescale when some row's max grew by > 8 nats (11.5 log2)
  if (__any(pmax > m_i + 11.5f)) {
    float mx = fmaxf(pmax, __shfl_xor(pmax, 16));
    mx = fmaxf(mx, __shfl_xor(mx, 32));
    float mnew = fmaxf(m_i, mx);
    float scl = exp2f(m_i - mnew);
    m_i = mnew;
    l_i *= scl;
#pragma unroll
    for (int r = 0; r < 4; ++r) {
      float so = __shfl(scl, lg * 4 + r);
#pragma unroll
      for (int dt = 0; dt < 4; ++dt) accO[dt][r] *= so;
    }
  }

#pragma unroll
  for (int nt = 0; nt < 4; ++nt) {
    float p0 = exp2f(s[nt][0] - m_i);
    float p1 = exp2f(s[nt][1] - m_i);
    float p2 = exp2f(s[nt][2] - m_i);
    float p3 = exp2f(s[nt][3] - m_i);
    l_i += (p0 + p1) + (p2 + p3);  // per-lane partial; reduced in epilogue
    uint2 wv;
    wv.x = cvt_pk_bf16(p0, p1);
    wv.y = cvt_pk_bf16(p2, p3);
    *(uint2*)(PTw + lr * 128 + (((2 * nt + (lg >> 1)) ^ x7) * 16) + ((2 * lg) & 3) * 4) = wv;
  }

  __builtin_amdgcn_s_setprio(1);
#pragma unroll
  for (int kk = 0; kk < 2; ++kk) {
    short8 pf = *(const short8*)(PTw + lr * 128 + (((4 * kk + lg) ^ x7) * 16));
#pragma unroll
    for (int dt = 0; dt < 4; ++dt) {
      short8 vf = *(const short8*)(Vb + (dt * 16 + lr) * 128 + (((4 * kk + lg) ^ x7) * 16));
      accO[dt] = __builtin_amdgcn_mfma_f32_16x16x32_bf16(pf, vf, accO[dt], 0, 0, 0);
    }
  }
  __builtin_amdgcn_s_setprio(0);
}

__global__ __launch_bounds__(256, 4) void attn_fwd(
    const unsigned short* __restrict__ qb, const unsigned short* __restrict__ kb,
    const unsigned short* __restrict__ vtb, unsigned short* __restrict__ ob) {
  __shared__ __align__(16) char Kbuf[2][8192];
  __shared__ __align__(16) char Vbuf[2][8192];
  __shared__ __align__(16) char PTbuf[4][2048];

  // XCD-local remap: all 16 q-tile blocks of one bh land on one XCD
  const int F = blockIdx.y * 16 + blockIdx.x;  // 0..1023
  const int c = F & 7, t = F >> 3;
  const int bh = c * 8 + (t >> 4);
  const int pr = t & 15;

  const int tid = threadIdx.x;
  const int wave = tid >> 6, lane = tid & 63;
  const int lr = lane & 15, lg = lane >> 4;
  const unsigned short* Q = qb + (long)bh * 2048 * 64;
  const char* Kp = (const char*)(kb + (long)bh * 2048 * 64);
  const char* Vt = (const char*)(vtb + (long)bh * 64 * 2048);
  const int b = bh >> 4, h = bh & 15;
  char* PTw = PTbuf[wave];

  floatx4 zero = {0.f, 0.f, 0.f, 0.f};

#pragma unroll 1
  for (int half = 0; half < 2; ++half) {
    const int qt = half ? (31 - pr) : pr;
    const int q0 = qt * 64 + wave * 16;
    const int nkv = qt + 1;

    short8 qf0 = *(const short8*)(Q + (q0 + lr) * 64 + lg * 8);
    short8 qf1 = *(const short8*)(Q + (q0 + lr) * 64 + 32 + lg * 8);

    floatx4 accO[4];
#pragma unroll
    for (int dt = 0; dt < 4; ++dt) accO[dt] = zero;
    float m_i = -1e30f, l_i = 0.f;

    stage_kv(Kbuf[0], Vbuf[0], Kp, Vt, 0, tid);
    __syncthreads();
#pragma unroll 1
    for (int kv = 0; kv < nkv; ++kv) {
      if (kv + 1 < nkv)
        stage_kv(Kbuf[(kv + 1) & 1], Vbuf[(kv + 1) & 1], Kp, Vt, (kv + 1) * 64, tid);
      attn_step(Kbuf[kv & 1], Vbuf[kv & 1], PTw, qf0, qf1, kv * 64, q0, lr, lg,
                kv == qt, m_i, l_i, accO);
      __syncthreads();
    }

    // epilogue: reduce per-lane partial l across the 4 lane-groups of a row
    float lt = l_i + __shfl_xor(l_i, 16);
    lt += __shfl_xor(lt, 32);
    float linv = 1.f / lt;
#pragma unroll
    for (int r = 0; r < 4; ++r) {
      float io = __shfl(linv, lg * 4 + r);
      int tq = q0 + 4 * lg + r;
#pragma unroll
      for (int dt = 0; dt < 4; ++dt)
        ob[((long)b * 2048 + tq) * 1024 + h * 64 + dt * 16 + lr] =
            f2bf(accO[dt][r] * io);
    }
  }
}

// ---------------------------------------------------------------------------
extern "C" void kernel_launch(void* const* d_in, const int* in_sizes, int n_in,
                              void* d_out, int out_size, void* d_ws, size_t ws_size,
                              hipStream_t stream) {
  const float* x = (const float*)d_in[0];
  const float* bq = (const float*)d_in[2];
  const float* bk = (const float*)d_in[4];
  const float* bv = (const float*)d_in[6];
  const float* bo = (const float*)d_in[8];
  float* out = (float*)d_out;

  char* ws = (char*)d_ws;
  unsigned short* xb = (unsigned short*)(ws);                  // 16 MB  [8192][1024]
  unsigned short* wqkv = (unsigned short*)(ws + (16l << 20));  // 6 MB   [3072][1024]
  unsigned short* wob = (unsigned short*)(ws + (22l << 20));   // 2 MB   [1024][1024]
  unsigned short* qb = (unsigned short*)(ws + (24l << 20));    // 16 MB  [64][2048][64]
  unsigned short* kb = (unsigned short*)(ws + (40l << 20));    // 16 MB  [64][2048][64]
  unsigned short* vtb = (unsigned short*)(ws + (56l << 20));   // 16 MB  [64][64][2048]
  unsigned short* ob = (unsigned short*)(ws + (72l << 20));    // 16 MB  [8192][1024]

  f2b_kernel<<<2097152 / 256, 256, 0, stream>>>(x, xb, 2097152);
  f2b_kernel<<<262144 / 256, 256, 0, stream>>>((const float*)d_in[1], wqkv, 262144);
  f2b_kernel<<<262144 / 256, 256, 0, stream>>>((const float*)d_in[3], wqkv + (1l << 20), 262144);
  f2b_kernel<<<262144 / 256, 256, 0, stream>>>((const float*)d_in[5], wqkv + (2l << 20), 262144);
  f2b_kernel<<<262144 / 256, 256, 0, stream>>>((const float*)d_in[7], wob, 262144);

  qkv_gemm<<<dim3(64, 24), 256, 0, stream>>>(xb, wqkv, bq, bk, bv, qb, kb, vtb);
  attn_fwd<<<dim3(16, 64), 256, 0, stream>>>(qb, kb, vtb, ob);
  out_gemm<<<dim3(64, 8), 256, 0, stream>>>(ob, wob, bo, out);
}